// Round 12
// baseline (262.477 us; speedup 1.0000x reference)
//
#include <hip/hip_runtime.h>
#include <cstdint>

typedef unsigned short u16;
typedef __attribute__((ext_vector_type(8))) short short8;
typedef __attribute__((ext_vector_type(4))) float float4v;

__device__ __forceinline__ float bf2f(u16 u) {
    union { unsigned int i; float f; } v; v.i = ((unsigned int)u) << 16; return v.f;
}
__device__ __forceinline__ u16 f2bf(float f) {
    union { float f; unsigned int i; } v; v.f = f;
    unsigned int i = v.i;
    i += 0x7fffu + ((i >> 16) & 1u);   // round-to-nearest-even
    return (u16)(i >> 16);
}
__device__ __forceinline__ u16 f2bf_t(float f) {   // truncating (P only)
    union { float f; unsigned int i; } v; v.f = f;
    return (u16)(v.i >> 16);
}
__device__ __forceinline__ uint4 cvt8(const float* __restrict__ p) {
    float4 a = *(const float4*)p;
    float4 b = *(const float4*)(p + 4);
    u16 t[8] = {f2bf(a.x), f2bf(a.y), f2bf(a.z), f2bf(a.w),
                f2bf(b.x), f2bf(b.y), f2bf(b.z), f2bf(b.w)};
    return *(const uint4*)t;
}
// async global->LDS, 16B per lane; lane i lands at base+16*i (m97-verified map)
__device__ __forceinline__ void gload16(const void* g, void* l) {
    __builtin_amdgcn_global_load_lds(
        (const __attribute__((address_space(1))) unsigned int*)g,
        (__attribute__((address_space(3))) unsigned int*)l, 16, 0, 0);
}

// ---------------------------------------------------------------------------
// x fp32 -> bf16, then zero the source (x becomes the O-accumulator).
// ---------------------------------------------------------------------------
__global__ void cvt_x_zero(float* __restrict__ src, u16* __restrict__ dst, int n8) {
    int i = blockIdx.x * blockDim.x + threadIdx.x;
    if (i >= n8) return;
    float* p = src + (size_t)i * 8;
    *(uint4*)(dst + (size_t)i * 8) = cvt8(p);
    float4 z = {0.f, 0.f, 0.f, 0.f};
    *(float4*)p = z; *(float4*)(p + 4) = z;
}

__global__ void cvt_f32_bf16(const float* __restrict__ src, u16* __restrict__ dst, int n8) {
    int i = blockIdx.x * blockDim.x + threadIdx.x;
    if (i >= n8) return;
    *(uint4*)(dst + (size_t)i * 8) = cvt8(src + (size_t)i * 8);
}

// Wo convert + zero lac (runs after gemm_qkv so the wq overlay is dead).
__global__ void cvt_wo_zero(const float* __restrict__ src, u16* __restrict__ dst,
                            float* __restrict__ lac) {
    int i = blockIdx.x * blockDim.x + threadIdx.x;   // 131072 threads
    *(uint4*)(dst + (size_t)i * 8) = cvt8(src + (size_t)i * 8);
    if (i < 16384) {
        float4 z = {0.f, 0.f, 0.f, 0.f};
        *(float4*)(lac + (size_t)i * 4) = z;
    }
}

// ---------------------------------------------------------------------------
// bf16 GEMM via global_load_lds (m97 structure): C[m,n]=sum_k A[m,k]*B[n,k].
// 128x128 tile, BK=32, 4 waves; unpadded LDS stride 32 (glds constraint).
// ---------------------------------------------------------------------------
__global__ __launch_bounds__(256) void gemm_bt(const u16* __restrict__ A,
                                               const u16* __restrict__ B,
                                               u16* __restrict__ C,
                                               int M, int N, int K) {
    __shared__ u16 As[128 * 32];
    __shared__ u16 Bs[128 * 32];
    const int tid  = threadIdx.x;
    const int wave = tid >> 6, lane = tid & 63;
    const int lg = lane >> 4, lr = lane & 15;
    const int bm = blockIdx.x * 128, bn = blockIdx.y * 128;
    const int wm = (wave & 1) * 64, wn = (wave >> 1) * 64;
    const int grow = lane >> 2;          // 0..15
    const int gcol = (lane & 3) * 8;

    float4v acc[4][4] = {};

    for (int k0 = 0; k0 < K; k0 += 32) {
        #pragma unroll
        for (int it = 0; it < 2; ++it) {
            int n = wave * 2 + it;                       // 0..7: 16-row slab
            int row = n * 16 + grow;
            gload16(A + (size_t)(bm + row) * K + k0 + gcol, As + n * 512 + lane * 8);
            gload16(B + (size_t)(bn + row) * K + k0 + gcol, Bs + n * 512 + lane * 8);
        }
        __syncthreads();

        short8 af[4], bf[4];
        #pragma unroll
        for (int i = 0; i < 4; ++i)
            af[i] = *(const short8*)(As + (wm + i * 16 + lr) * 32 + lg * 8);
        #pragma unroll
        for (int j = 0; j < 4; ++j)
            bf[j] = *(const short8*)(Bs + (wn + j * 16 + lr) * 32 + lg * 8);
        #pragma unroll
        for (int i = 0; i < 4; ++i)
            #pragma unroll
            for (int j = 0; j < 4; ++j)
                acc[i][j] = __builtin_amdgcn_mfma_f32_16x16x32_bf16(af[i], bf[j], acc[i][j], 0, 0, 0);
        __syncthreads();
    }

    #pragma unroll
    for (int i = 0; i < 4; ++i)
        #pragma unroll
        for (int j = 0; j < 4; ++j)
            #pragma unroll
            for (int r = 0; r < 4; ++r) {
                int row = bm + wm + i * 16 + lg * 4 + r;
                int col = bn + wn + j * 16 + lr;
                C[(size_t)row * N + col] = f2bf(acc[i][j][r]);
            }
}

// ---------------------------------------------------------------------------
// RoPE in place; q gets 0.125*log2(e) so attn can use native exp2. pos int32.
// ---------------------------------------------------------------------------
__global__ void rope_kernel(u16* __restrict__ qkv, const int* __restrict__ pos, int S) {
    int idx = blockIdx.x * blockDim.x + threadIdx.x;
    int s = idx >> 10;
    if (s >= S) return;
    int p    = idx & 1023;
    int part = p >> 9;
    int wi   = p & 511;
    int head = wi >> 5;
    int i    = wi & 31;
    int col  = part * 1024 + head * 64 + 2 * i;

    u16* ptr = qkv + (size_t)s * 3072 + col;
    ushort2 v = *(const ushort2*)ptr;
    float xe = bf2f(v.x), xo = bf2f(v.y);
    float freq = __expf(-(float)i * 0.2878231366242557f);
    float ang  = (float)pos[s] * freq;
    float sn = sinf(ang), cs = cosf(ang);
    float re = xe * cs - xo * sn;
    float ro = xe * sn + xo * cs;
    if (part == 0) { re *= 0.18033688011112042f; ro *= 0.18033688011112042f; }  // 0.125*log2e
    ushort2 o; o.x = f2bf(re); o.y = f2bf(ro);
    *(ushort2*)ptr = o;
}

// ---------------------------------------------------------------------------
// V transpose: VT[h][d][s] = qkv[s][2048 + h*64 + d]. (verified r9)
// ---------------------------------------------------------------------------
__global__ __launch_bounds__(256) void transpose_v(const u16* __restrict__ qkv,
                                                   u16* __restrict__ VT) {
    __shared__ u16 T[64 * 65];
    const int h = blockIdx.y, s0 = blockIdx.x * 64;
    const int tid = threadIdx.x;
    #pragma unroll
    for (int i = 0; i < 2; ++i) {
        int seg = i * 256 + tid;
        int r = seg >> 3, c8 = (seg & 7) * 8;
        u16 tmp[8];
        *(uint4*)tmp = *(const uint4*)(qkv + (size_t)(s0 + r) * 3072 + 2048 + h * 64 + c8);
        #pragma unroll
        for (int j = 0; j < 8; ++j) T[r * 65 + c8 + j] = tmp[j];
    }
    __syncthreads();
    #pragma unroll
    for (int i = 0; i < 2; ++i) {
        int seg = i * 256 + tid;
        int d = seg >> 3, s8 = (seg & 7) * 8;
        u16 tmp[8];
        #pragma unroll
        for (int j = 0; j < 8; ++j) tmp[j] = T[(s8 + j) * 65 + d];
        *(uint4*)(VT + (size_t)(h * 64 + d) * 4096 + s0 + s8) = *(const uint4*)tmp;
    }
}

// ---------------------------------------------------------------------------
// Split-K flash attention (structure verified r11). Changes: native exp2
// (scale pre-folded into q), truncating P convert.
// ---------------------------------------------------------------------------
__global__ __launch_bounds__(512) void attn_kernel(const u16* __restrict__ qkv,
                                                   const u16* __restrict__ VT,
                                                   float* __restrict__ acc,
                                                   float* __restrict__ lac) {
    __shared__ u16 Ks[64 * 64];
    __shared__ u16 Vt[64 * 64];
    __shared__ u16 Ps[8][16 * 72];

    const int tid  = threadIdx.x;
    const int wave = tid >> 6, lane = tid & 63;
    const int lg = lane >> 4, lr = lane & 15;
    const int h  = blockIdx.y;
    const int z  = blockIdx.z;

    const int srow = tid >> 3;
    const int sg   = tid & 7;
    const int sco  = sg * 8;
    const int sldso = srow * 64 + ((sg ^ (srow & 7)) * 8);
    const int swz = (lr & 7);

    #pragma unroll 1
    for (int part = 0; part < 2; ++part) {
        const int qt = part ? (31 - (int)blockIdx.x) : (int)blockIdx.x;
        const int qb = qt * 128;
        const int qrow0 = qb + wave * 16;
        const int tmax = qb + 64;
        const int t0s  = z * 64;

        short8 qf[2];
        #pragma unroll
        for (int kk = 0; kk < 2; ++kk)
            qf[kk] = *(const short8*)(qkv + (size_t)(qrow0 + lr) * 3072 + h * 64 + kk * 32 + lg * 8);

        float4v o_acc[4] = {};
        float rs = 0.f;

        uint4 rK = *(const uint4*)(qkv + (size_t)(t0s + srow) * 3072 + 1024 + h * 64 + sco);
        uint4 rV = *(const uint4*)(VT + (size_t)(h * 64 + srow) * 4096 + t0s + sco);
        __syncthreads();
        *(uint4*)(Ks + sldso) = rK;
        *(uint4*)(Vt + sldso) = rV;
        __syncthreads();

        for (int t0 = t0s; t0 <= tmax; t0 += 128) {
            const bool hasnext = (t0 + 128 <= tmax);
            if (hasnext) {
                rK = *(const uint4*)(qkv + (size_t)(t0 + 128 + srow) * 3072 + 1024 + h * 64 + sco);
                rV = *(const uint4*)(VT + (size_t)(h * 64 + srow) * 4096 + t0 + 128 + sco);
            }

            float4v sc[4];
            #pragma unroll
            for (int jt = 0; jt < 4; ++jt) {
                float4v a = {};
                #pragma unroll
                for (int kk = 0; kk < 2; ++kk) {
                    short8 kf = *(const short8*)(Ks + (jt * 16 + lr) * 64 + (((kk * 4 + lg) ^ swz) * 8));
                    a = __builtin_amdgcn_mfma_f32_16x16x32_bf16(kf, qf[kk], a, 0, 0, 0);
                }
                sc[jt] = a;
            }

            const bool mk = (t0 + 63 > qrow0);
            const int q_abs = qrow0 + lr;
            #pragma unroll
            for (int jt = 0; jt < 4; ++jt) {
                u16 pt[4];
                #pragma unroll
                for (int r = 0; r < 4; ++r) {
                    float s = sc[jt][r];
                    if (mk && (t0 + jt * 16 + lg * 4 + r > q_abs)) s = -30000.f;
                    float p = exp2f(fminf(s, 80.f));   // native v_exp_f32
                    rs += p;
                    pt[r] = f2bf_t(p);
                }
                *(uint2*)(Ps[wave] + lr * 72 + jt * 16 + lg * 4) = *(const uint2*)pt;
            }

            short8 pf[2];
            #pragma unroll
            for (int kk = 0; kk < 2; ++kk)
                pf[kk] = *(const short8*)(Ps[wave] + lr * 72 + kk * 32 + lg * 8);
            #pragma unroll
            for (int jd = 0; jd < 4; ++jd) {
                float4v a = o_acc[jd];
                #pragma unroll
                for (int kk = 0; kk < 2; ++kk) {
                    short8 vf = *(const short8*)(Vt + (jd * 16 + lr) * 64 + (((kk * 4 + lg) ^ swz) * 8));
                    a = __builtin_amdgcn_mfma_f32_16x16x32_bf16(pf[kk], vf, a, 0, 0, 0);
                }
                o_acc[jd] = a;
            }
            __syncthreads();
            if (hasnext) {
                *(uint4*)(Ks + sldso) = rK;
                *(uint4*)(Vt + sldso) = rV;
            }
            __syncthreads();
        }

        float t = rs;
        t += __shfl_xor(t, 16, 64);
        t += __shfl_xor(t, 32, 64);
        if (lane < 16)
            atomicAdd(&lac[(size_t)(qrow0 + lr) * 16 + h], t);

        #pragma unroll
        for (int jd = 0; jd < 4; ++jd)
            #pragma unroll
            for (int r = 0; r < 4; ++r) {
                int s = qrow0 + lg * 4 + r;
                int d = jd * 16 + lr;
                atomicAdd(&acc[(size_t)s * 1024 + h * 64 + d], o_acc[jd][r]);
            }
    }
}

// ---------------------------------------------------------------------------
// Out-projection with fused normalization: C_f32[m,n] = sum_k (acc[m,k]/l[m,h])
// * Wo_bf16[n,k]. A staged from fp32 acc (normalize+cvt inline, padded LDS);
// B via global_load_lds (unpadded).
// ---------------------------------------------------------------------------
__global__ __launch_bounds__(256) void gemm_oproj(const float* __restrict__ acc_,
                                                  const float* __restrict__ lac,
                                                  const u16* __restrict__ B,
                                                  float* __restrict__ C) {
    __shared__ u16 As[128 * 40];
    __shared__ u16 Bs[128 * 32];
    const int tid  = threadIdx.x;
    const int wave = tid >> 6, lane = tid & 63;
    const int lg = lane >> 4, lr = lane & 15;
    const int bm = blockIdx.x * 128, bn = blockIdx.y * 128;
    const int wm = (wave & 1) * 64, wn = (wave >> 1) * 64;
    const int grow = lane >> 2;
    const int gcol = (lane & 3) * 8;

    const int row0 = tid >> 2, row1 = row0 + 64;     // this thread's two A rows
    const int co   = (tid & 3) * 8;
    float inv0 = 0.f, inv1 = 0.f;

    float4v acc[4][4] = {};

    for (int k0 = 0; k0 < 1024; k0 += 32) {
        if ((k0 & 63) == 0) {                        // h = k0>>6 changes every 2 iters
            int hh = k0 >> 6;
            inv0 = 1.0f / lac[(size_t)(bm + row0) * 16 + hh];
            inv1 = 1.0f / lac[(size_t)(bm + row1) * 16 + hh];
        }
        {   // A: normalize fp32 acc -> bf16
            const float* p0 = acc_ + (size_t)(bm + row0) * 1024 + k0 + co;
            const float* p1 = acc_ + (size_t)(bm + row1) * 1024 + k0 + co;
            float4 a0 = *(const float4*)p0, b0 = *(const float4*)(p0 + 4);
            float4 a1 = *(const float4*)p1, b1 = *(const float4*)(p1 + 4);
            u16 t0[8] = {f2bf(a0.x*inv0), f2bf(a0.y*inv0), f2bf(a0.z*inv0), f2bf(a0.w*inv0),
                         f2bf(b0.x*inv0), f2bf(b0.y*inv0), f2bf(b0.z*inv0), f2bf(b0.w*inv0)};
            u16 t1[8] = {f2bf(a1.x*inv1), f2bf(a1.y*inv1), f2bf(a1.z*inv1), f2bf(a1.w*inv1),
                         f2bf(b1.x*inv1), f2bf(b1.y*inv1), f2bf(b1.z*inv1), f2bf(b1.w*inv1)};
            *(uint4*)(As + row0 * 40 + co) = *(const uint4*)t0;
            *(uint4*)(As + row1 * 40 + co) = *(const uint4*)t1;
        }
        #pragma unroll
        for (int it = 0; it < 2; ++it) {
            int n = wave * 2 + it;
            int row = n * 16 + grow;
            gload16(B + (size_t)(bn + row) * 1024 + k0 + gcol, Bs + n * 512 + lane * 8);
        }
        __syncthreads();

        short8 af[4], bf[4];
        #pragma unroll
        for (int i = 0; i < 4; ++i)
            af[i] = *(const short8*)(As + (wm + i * 16 + lr) * 40 + lg * 8);
        #pragma unroll
        for (int j = 0; j < 4; ++j)
            bf[j] = *(const short8*)(Bs + (wn + j * 16 + lr) * 32 + lg * 8);
        #pragma unroll
        for (int i = 0; i < 4; ++i)
            #pragma unroll
            for (int j = 0; j < 4; ++j)
                acc[i][j] = __builtin_amdgcn_mfma_f32_16x16x32_bf16(af[i], bf[j], acc[i][j], 0, 0, 0);
        __syncthreads();
    }

    #pragma unroll
    for (int i = 0; i < 4; ++i)
        #pragma unroll
        for (int j = 0; j < 4; ++j)
            #pragma unroll
            for (int r = 0; r < 4; ++r) {
                int row = bm + wm + i * 16 + lg * 4 + r;
                int col = bn + wn + j * 16 + lr;
                C[(size_t)row * 1024 + col] = acc[i][j][r];
            }
}

__global__ void fill_diag(float* __restrict__ p, size_t n, float mark) {
    size_t i = (size_t)blockIdx.x * blockDim.x + threadIdx.x;
    if (i < n) p[i] = 0.f;
    if (i == 0) p[0] = mark;
}

// ---------------------------------------------------------------------------
extern "C" void kernel_launch(void* const* d_in, const int* in_sizes, int n_in,
                              void* d_out, int out_size, void* d_ws, size_t ws_size,
                              hipStream_t stream) {
    int ix = -1, iwq = -1, iwo = -1, ip = -1;
    for (int i = 0; i < n_in; ++i) {
        if      (in_sizes[i] == 4096 * 1024) ix = i;
        else if (in_sizes[i] == 3072 * 1024) iwq = i;
        else if (in_sizes[i] == 1024 * 1024) iwo = i;
        else if (in_sizes[i] == 4096)        ip = i;
    }
    float* out = (float*)d_out;
    const size_t OUT_E = (size_t)4096 * 1024;
    const size_t QKV_E = (size_t)4096 * 3072;
    const size_t NEED  = QKV_E * 2 + (size_t)3072 * 1024 * 2;   // 31.46 MB (proven)

    if (ix < 0 || iwq < 0 || iwo < 0 || ip < 0 || out_size != (int)OUT_E) {
        fill_diag<<<(int)((OUT_E + 255) / 256), 256, 0, stream>>>(out, OUT_E, 1000.0f);
        return;
    }
    if (ws_size < NEED) {
        fill_diag<<<(int)((OUT_E + 255) / 256), 256, 0, stream>>>(out, OUT_E, 500.0f);
        return;
    }
    float* x          = (float*)d_in[ix];        // doubles as O-accumulator after cvt
    const float* Wqkv = (const float*)d_in[iwq];
    const float* Wo   = (const float*)d_in[iwo];
    const int*   pos  = (const int*)d_in[ip];

    u16* qkv   = (u16*)d_ws;                    // [4096][3072] bf16
    u16* wq_bf = (u16*)d_ws + QKV_E;            // [3072][1024] bf16 (dead after gemm_qkv)
    u16* wo_bf = wq_bf;                         // overlay (2 MB)
    float* lac = (float*)((char*)wq_bf + 2 * 1024 * 1024 + 65536);  // [4096][16] f32
    u16* x_bf  = (u16*)d_out;                   // d_out lo (dead after gemm_qkv)
    u16* VT    = (u16*)d_out + OUT_E;           // d_out hi: [16][64][4096] bf16
    float* acc = x;

    cvt_x_zero<<<2048, 256, 0, stream>>>(x, x_bf, 4096 * 1024 / 8);
    cvt_f32_bf16<<<1536, 256, 0, stream>>>(Wqkv, wq_bf, 3072 * 1024 / 8);
    gemm_bt<<<dim3(32, 24), 256, 0, stream>>>(x_bf, wq_bf, qkv, 4096, 3072, 1024);
    cvt_wo_zero<<<512, 256, 0, stream>>>(Wo, wo_bf, lac);   // after gemm: wq dead
    rope_kernel<<<16384, 256, 0, stream>>>(qkv, pos, 4096);
    transpose_v<<<dim3(64, 16), 256, 0, stream>>>(qkv, VT);
    attn_kernel<<<dim3(16, 16, 2), 512, 0, stream>>>(qkv, VT, acc, lac);
    gemm_oproj<<<dim3(32, 8), 256, 0, stream>>>(acc, lac, wo_bf, out);
}